// Round 1
// 666.127 us; speedup vs baseline: 1.0233x; 1.0233x over previous
//
#include <hip/hip_runtime.h>
#include <math.h>

// Problem constants (from reference setup_inputs)
#define BB   8
#define HH   32
#define KVHH 8
#define DD   128
#define PSZ  16
#define LMAX 4096
#define CHUNK 256
#define NCHUNK (LMAX / CHUNK)   // 16

// cache shape: (pages, 2, KVH, PAGE_SIZE, D), fp32
#define PAGE_STRIDE (2 * KVHH * PSZ * DD)   // 32768 floats
#define KV_OFFSET   (KVHH * PSZ * DD)       // 16384 floats (K -> V)
#define HEAD_STRIDE (PSZ * DD)              // 2048 floats

// Partial kernel: grid = B*H*NCHUNK blocks, 256 threads (8 half-waves of 32).
// Phase-split design: (A) all 256 scores via K-only streaming, (M) one block
// max + exp2, (B) pure p*V FMA streaming. Removes the per-row online-softmax
// dependent chain from the V loop so loads pipeline freely.
__global__ __launch_bounds__(256) void attn_partial(
    const float* __restrict__ q,
    const float* __restrict__ cache,
    const int*   __restrict__ indptr,
    const int*   __restrict__ pageind,
    const int*   __restrict__ sind,
    const int*   __restrict__ snnz,
    float* __restrict__ ws_m,      // [B*H][NCHUNK]
    float* __restrict__ ws_l,      // [B*H][NCHUNK]
    float* __restrict__ ws_acc)    // [B*H][NCHUNK][D]
{
    // XCD-grouping swizzle: all 64 blocks (4 heads x 16 chunks) of one
    // (b,kvh) group land on one XCD (assumes blk%8 -> XCD round-robin;
    // wrong mapping only costs locality, never correctness).
    const int blk   = blockIdx.x;          // 4096 = 8 super * 64 slot * 8 xcd
    const int xcd   = blk & 7;
    const int slot  = (blk >> 3) & 63;
    const int super = blk >> 9;
    const int g     = super * 8 + xcd;     // (b,kvh) group id, 0..63
    const int b     = g >> 3;
    const int kvh   = g & 7;
    const int h     = (kvh << 2) + (slot >> 4);  // groups = H/KVH = 4
    const int chunk = slot & 15;
    const int bh    = b * HH + h;
    const int tid   = threadIdx.x;

    const int nnz  = snnz[bh];
    const int l0   = chunk * CHUNK;
    const int widx = bh * NCHUNK + chunk;

    if (l0 >= nnz) {
        if (tid == 0) { ws_m[widx] = -1e30f; ws_l[widx] = 0.0f; }
        if (tid < DD) ws_acc[widx * DD + tid] = 0.0f;
        return;
    }
    const int nrows = min(nnz - l0, CHUNK);
    const int nr32  = (nrows + 31) & ~31;   // rows processed (padded, p=0)

    __shared__ unsigned s_base[CHUNK];
    __shared__ float    s_p[CHUNK];
    __shared__ float    s_red[16];          // [0..3] wave max, [8..11] wave sum
    __shared__ float    s_acc[8][DD];

    // Phase 0: resolve sparse_ind -> cache row base offsets (coalesced).
    const int indbase = indptr[b];
    const int* si = sind + bh * LMAX + l0;
    {
        unsigned base = 0u;                 // pad rows read row 0 (harmless)
        if (tid < nrows) {
            const int idx = si[tid];
            const int pid = pageind[indbase + (idx >> 4)];
            base = (unsigned)pid * PAGE_STRIDE
                 + (unsigned)(kvh * HEAD_STRIDE + (idx & 15) * DD);
        }
        s_base[tid] = base;
    }
    __syncthreads();

    const int lane32 = tid & 31;
    const int hw     = tid >> 5;            // 0..7
    const float4 q4  = *(const float4*)(q + bh * DD + lane32 * 4);
    const float cscale = 0.08838834764831845f * 1.4426950408889634f; // 1/sqrt(128)*log2(e)

    // ---- Phase A: all scores. 4 independent rows in flight per half-wave.
    for (int i = hw; i < nr32; i += 32) {
        const unsigned b0 = s_base[i];
        const unsigned b1 = s_base[i + 8];
        const unsigned b2 = s_base[i + 16];
        const unsigned b3 = s_base[i + 24];
        const float4 k0 = *(const float4*)(cache + b0 + lane32 * 4);
        const float4 k1 = *(const float4*)(cache + b1 + lane32 * 4);
        const float4 k2 = *(const float4*)(cache + b2 + lane32 * 4);
        const float4 k3 = *(const float4*)(cache + b3 + lane32 * 4);
        float s0 = k0.x*q4.x + k0.y*q4.y + k0.z*q4.z + k0.w*q4.w;
        float s1 = k1.x*q4.x + k1.y*q4.y + k1.z*q4.z + k1.w*q4.w;
        float s2 = k2.x*q4.x + k2.y*q4.y + k2.z*q4.z + k2.w*q4.w;
        float s3 = k3.x*q4.x + k3.y*q4.y + k3.z*q4.z + k3.w*q4.w;
        #pragma unroll
        for (int m = 16; m >= 1; m >>= 1) {   // 4 interleaved reduce chains
            s0 += __shfl_xor(s0, m);
            s1 += __shfl_xor(s1, m);
            s2 += __shfl_xor(s2, m);
            s3 += __shfl_xor(s3, m);
        }
        if (lane32 == 0) {
            s_p[i]      = (i      < nrows) ? s0 * cscale : -1e30f;
            s_p[i + 8]  = (i + 8  < nrows) ? s1 * cscale : -1e30f;
            s_p[i + 16] = (i + 16 < nrows) ? s2 * cscale : -1e30f;
            s_p[i + 24] = (i + 24 < nrows) ? s3 * cscale : -1e30f;
        }
    }
    __syncthreads();

    // ---- Phase M: block max, p = exp2(s - M), l = sum p.
    const float sc = (tid < nr32) ? s_p[tid] : -1e30f;
    float wm = sc;
    #pragma unroll
    for (int m = 32; m >= 1; m >>= 1) wm = fmaxf(wm, __shfl_xor(wm, m));
    const int wv = tid >> 6;
    if ((tid & 63) == 0) s_red[wv] = wm;
    __syncthreads();
    const float M = fmaxf(fmaxf(s_red[0], s_red[1]), fmaxf(s_red[2], s_red[3]));
    const float p = (tid < nr32) ? exp2f(sc - M) : 0.0f;   // pads -> exactly 0
    if (tid < nr32) s_p[tid] = p;         // own slot only; safe before barrier
    float wl = p;
    #pragma unroll
    for (int m = 32; m >= 1; m >>= 1) wl += __shfl_xor(wl, m);
    if ((tid & 63) == 0) s_red[8 + wv] = wl;  // disjoint from s_red[0..3] reads
    __syncthreads();

    // ---- Phase B: pure streaming p*V accumulate (only dep: 4-cycle FMA chain).
    float4 acc = make_float4(0.f, 0.f, 0.f, 0.f);
    for (int i = hw; i < nr32; i += 32) {
        const unsigned b0 = s_base[i];
        const unsigned b1 = s_base[i + 8];
        const unsigned b2 = s_base[i + 16];
        const unsigned b3 = s_base[i + 24];
        const float p0 = s_p[i];
        const float p1 = s_p[i + 8];
        const float p2 = s_p[i + 16];
        const float p3 = s_p[i + 24];
        const float4 v0 = *(const float4*)(cache + b0 + KV_OFFSET + lane32 * 4);
        const float4 v1 = *(const float4*)(cache + b1 + KV_OFFSET + lane32 * 4);
        const float4 v2 = *(const float4*)(cache + b2 + KV_OFFSET + lane32 * 4);
        const float4 v3 = *(const float4*)(cache + b3 + KV_OFFSET + lane32 * 4);
        acc.x += p0*v0.x; acc.y += p0*v0.y; acc.z += p0*v0.z; acc.w += p0*v0.w;
        acc.x += p1*v1.x; acc.y += p1*v1.y; acc.z += p1*v1.z; acc.w += p1*v1.w;
        acc.x += p2*v2.x; acc.y += p2*v2.y; acc.z += p2*v2.z; acc.w += p2*v2.w;
        acc.x += p3*v3.x; acc.y += p3*v3.y; acc.z += p3*v3.z; acc.w += p3*v3.w;
    }

    *(float4*)&s_acc[hw][lane32 * 4] = acc;
    __syncthreads();

    if (tid < DD) {
        float a = 0.f;
        #pragma unroll
        for (int i = 0; i < 8; i++) a += s_acc[i][tid];
        ws_acc[widx * DD + tid] = a;
        if (tid == 0) {
            ws_m[widx] = M;
            ws_l[widx] = s_red[8] + s_red[9] + s_red[10] + s_red[11];
        }
    }
}

// Combine kernel: grid = B*H blocks, 128 threads; merge NCHUNK partials.
__global__ __launch_bounds__(128) void attn_combine(
    const float* __restrict__ ws_m,
    const float* __restrict__ ws_l,
    const float* __restrict__ ws_acc,
    float* __restrict__ out)
{
    const int bh = blockIdx.x;
    const int d  = threadIdx.x;

    float M = -1e30f;
    #pragma unroll
    for (int i = 0; i < NCHUNK; i++) M = fmaxf(M, ws_m[bh * NCHUNK + i]);

    float tot = 0.f, a = 0.f;
    #pragma unroll
    for (int i = 0; i < NCHUNK; i++) {
        const float f = exp2f(ws_m[bh * NCHUNK + i] - M);
        tot += ws_l[bh * NCHUNK + i] * f;
        a   += ws_acc[(bh * NCHUNK + i) * DD + d] * f;
    }
    out[bh * DD + d] = a / tot;
}

extern "C" void kernel_launch(void* const* d_in, const int* in_sizes, int n_in,
                              void* d_out, int out_size, void* d_ws, size_t ws_size,
                              hipStream_t stream) {
    const float* q      = (const float*)d_in[0];
    const float* cache  = (const float*)d_in[1];
    const int*   indptr = (const int*)d_in[2];
    const int*   pgind  = (const int*)d_in[3];
    const int*   sind   = (const int*)d_in[4];
    const int*   snnz   = (const int*)d_in[5];
    float* out = (float*)d_out;

    // workspace layout: m[256*16], l[256*16], acc[256*16*128]  (~2.1 MB)
    float* ws_m   = (float*)d_ws;
    float* ws_l   = ws_m + BB * HH * NCHUNK;
    float* ws_acc = ws_l + BB * HH * NCHUNK;

    attn_partial<<<dim3(BB * HH * NCHUNK), dim3(256), 0, stream>>>(
        q, cache, indptr, pgind, sind, snnz, ws_m, ws_l, ws_acc);
    attn_combine<<<dim3(BB * HH), dim3(128), 0, stream>>>(
        ws_m, ws_l, ws_acc, out);
}

// Round 2
// 662.009 us; speedup vs baseline: 1.0297x; 1.0062x over previous
//
#include <hip/hip_runtime.h>
#include <math.h>

// Problem constants (from reference setup_inputs)
#define BB   8
#define HH   32
#define KVHH 8
#define DD   128
#define PSZ  16
#define LMAX 4096
#define CHUNK 256
#define NCHUNK (LMAX / CHUNK)   // 16

// cache shape: (pages, 2, KVH, PAGE_SIZE, D), fp32
#define PAGE_STRIDE (2 * KVHH * PSZ * DD)   // 32768 floats
#define KV_OFFSET   (KVHH * PSZ * DD)       // 16384 floats (K -> V)
#define HEAD_STRIDE (PSZ * DD)              // 2048 floats

// Partial kernel: grid = B*H*NCHUNK blocks, 256 threads (8 half-waves of 32).
// Phase-split + deep-MLP design: (A) all scores with 8 rows (8KB) in flight
// per half-wave, software-pipelined so loads never wait on the shfl chain;
// (M) one block max + exp2; (B) p*V accumulate, also 8-deep pipelined, with
// the first V batch prefetched before phase M's barriers.
__global__ __launch_bounds__(256) void attn_partial(
    const float* __restrict__ q,
    const float* __restrict__ cache,
    const int*   __restrict__ indptr,
    const int*   __restrict__ pageind,
    const int*   __restrict__ sind,
    const int*   __restrict__ snnz,
    float* __restrict__ ws_m,      // [B*H][NCHUNK]
    float* __restrict__ ws_l,      // [B*H][NCHUNK]
    float* __restrict__ ws_acc)    // [B*H][NCHUNK][D]
{
    // XCD-grouping swizzle: all 64 blocks (4 heads x 16 chunks) of one
    // (b,kvh) group land on one XCD (assumes blk%8 -> XCD round-robin).
    const int blk   = blockIdx.x;          // 4096 = 8 super * 64 slot * 8 xcd
    const int xcd   = blk & 7;
    const int slot  = (blk >> 3) & 63;
    const int super = blk >> 9;
    const int g     = super * 8 + xcd;     // (b,kvh) group id, 0..63
    const int b     = g >> 3;
    const int kvh   = g & 7;
    const int h     = (kvh << 2) + (slot >> 4);  // groups = H/KVH = 4
    const int chunk = slot & 15;
    const int bh    = b * HH + h;
    const int tid   = threadIdx.x;

    const int nnz  = snnz[bh];
    const int l0   = chunk * CHUNK;
    const int widx = bh * NCHUNK + chunk;

    if (l0 >= nnz) {
        if (tid == 0) { ws_m[widx] = -1e30f; ws_l[widx] = 0.0f; }
        if (tid < DD) ws_acc[widx * DD + tid] = 0.0f;
        return;
    }
    const int nrows = min(nnz - l0, CHUNK);
    const int nr64  = (nrows + 63) & ~63;   // padded batch bound (64..256)
    const int nbat  = nr64 >> 6;            // 1..4 batches of 64 rows

    __shared__ unsigned s_base[CHUNK];
    __shared__ float    s_p[CHUNK];
    __shared__ float    s_red[16];          // [0..3] wave max, [8..11] wave sum
    __shared__ float    s_acc[8][DD];

    // Phase 0: resolve sparse_ind -> cache row base offsets (coalesced).
    const int indbase = indptr[b];
    const int* si = sind + bh * LMAX + l0;
    {
        unsigned base = 0u;                 // pad rows read row 0 (harmless)
        if (tid < nrows) {
            const int idx = si[tid];
            const int pid = pageind[indbase + (idx >> 4)];
            base = (unsigned)pid * PAGE_STRIDE
                 + (unsigned)(kvh * HEAD_STRIDE + (idx & 15) * DD);
        }
        s_base[tid] = base;
    }
    __syncthreads();

    const int lane32 = tid & 31;
    const int hw     = tid >> 5;            // 0..7
    const float4 q4  = *(const float4*)(q + bh * DD + lane32 * 4);
    const float cscale = 0.08838834764831845f * 1.4426950408889634f; // 1/sqrt(128)*log2(e)

    // ---- Phase A: scores, 8 rows in flight per half-wave, pipelined.
    {
        float4 k[8];
        #pragma unroll
        for (int r = 0; r < 8; r++)
            k[r] = *(const float4*)(cache + s_base[hw + r * 8] + lane32 * 4);

        for (int t = 0; t < nbat; ++t) {
            const int i = hw + (t << 6);
            float4 kn[8];
            if (t + 1 < nbat) {
                #pragma unroll
                for (int r = 0; r < 8; r++)
                    kn[r] = *(const float4*)(cache + s_base[i + 64 + r * 8] + lane32 * 4);
            }
            float s[8];
            #pragma unroll
            for (int r = 0; r < 8; r++)
                s[r] = k[r].x*q4.x + k[r].y*q4.y + k[r].z*q4.z + k[r].w*q4.w;
            #pragma unroll
            for (int m = 16; m >= 1; m >>= 1) {
                #pragma unroll
                for (int r = 0; r < 8; r++) s[r] += __shfl_xor(s[r], m);
            }
            if (lane32 == 0) {
                #pragma unroll
                for (int r = 0; r < 8; r++)
                    s_p[i + r * 8] = (i + r * 8 < nrows) ? s[r] * cscale : -1e30f;
            }
            if (t + 1 < nbat) {
                #pragma unroll
                for (int r = 0; r < 8; r++) k[r] = kn[r];
            }
        }
    }

    // Prefetch first V batch (rows hw + r*8 < 64 <= nr64 always) so the
    // HBM latency hides under phase M's barriers + reduce.
    float4 v[8];
    #pragma unroll
    for (int r = 0; r < 8; r++)
        v[r] = *(const float4*)(cache + s_base[hw + r * 8] + KV_OFFSET + lane32 * 4);

    __syncthreads();

    // ---- Phase M: block max, p = exp2(s - M), l = sum p.
    const float sc = (tid < nr64) ? s_p[tid] : -1e30f;
    float wm = sc;
    #pragma unroll
    for (int m = 32; m >= 1; m >>= 1) wm = fmaxf(wm, __shfl_xor(wm, m));
    const int wv = tid >> 6;
    if ((tid & 63) == 0) s_red[wv] = wm;
    __syncthreads();
    const float M = fmaxf(fmaxf(s_red[0], s_red[1]), fmaxf(s_red[2], s_red[3]));
    const float p = (tid < nr64) ? exp2f(sc - M) : 0.0f;   // pads -> exactly 0
    if (tid < nr64) s_p[tid] = p;         // own slot only; safe before barrier
    float wl = p;
    #pragma unroll
    for (int m = 32; m >= 1; m >>= 1) wl += __shfl_xor(wl, m);
    if ((tid & 63) == 0) s_red[8 + wv] = wl;  // disjoint from s_red[0..3] reads
    __syncthreads();

    // ---- Phase B: p*V accumulate, 8 rows in flight, pipelined (v preloaded).
    float4 acc = make_float4(0.f, 0.f, 0.f, 0.f);
    for (int t = 0; t < nbat; ++t) {
        const int i = hw + (t << 6);
        float4 vn[8];
        if (t + 1 < nbat) {
            #pragma unroll
            for (int r = 0; r < 8; r++)
                vn[r] = *(const float4*)(cache + s_base[i + 64 + r * 8] + KV_OFFSET + lane32 * 4);
        }
        #pragma unroll
        for (int r = 0; r < 8; r++) {
            const float pr = s_p[i + r * 8];
            acc.x += pr * v[r].x;
            acc.y += pr * v[r].y;
            acc.z += pr * v[r].z;
            acc.w += pr * v[r].w;
        }
        if (t + 1 < nbat) {
            #pragma unroll
            for (int r = 0; r < 8; r++) v[r] = vn[r];
        }
    }

    *(float4*)&s_acc[hw][lane32 * 4] = acc;
    __syncthreads();

    if (tid < DD) {
        float a = 0.f;
        #pragma unroll
        for (int i = 0; i < 8; i++) a += s_acc[i][tid];
        ws_acc[widx * DD + tid] = a;
        if (tid == 0) {
            ws_m[widx] = M;
            ws_l[widx] = s_red[8] + s_red[9] + s_red[10] + s_red[11];
        }
    }
}

// Combine kernel: grid = B*H blocks, 128 threads; merge NCHUNK partials.
__global__ __launch_bounds__(128) void attn_combine(
    const float* __restrict__ ws_m,
    const float* __restrict__ ws_l,
    const float* __restrict__ ws_acc,
    float* __restrict__ out)
{
    const int bh = blockIdx.x;
    const int d  = threadIdx.x;

    float M = -1e30f;
    #pragma unroll
    for (int i = 0; i < NCHUNK; i++) M = fmaxf(M, ws_m[bh * NCHUNK + i]);

    float tot = 0.f, a = 0.f;
    #pragma unroll
    for (int i = 0; i < NCHUNK; i++) {
        const float f = exp2f(ws_m[bh * NCHUNK + i] - M);
        tot += ws_l[bh * NCHUNK + i] * f;
        a   += ws_acc[(bh * NCHUNK + i) * DD + d] * f;
    }
    out[bh * DD + d] = a / tot;
}

extern "C" void kernel_launch(void* const* d_in, const int* in_sizes, int n_in,
                              void* d_out, int out_size, void* d_ws, size_t ws_size,
                              hipStream_t stream) {
    const float* q      = (const float*)d_in[0];
    const float* cache  = (const float*)d_in[1];
    const int*   indptr = (const int*)d_in[2];
    const int*   pgind  = (const int*)d_in[3];
    const int*   sind   = (const int*)d_in[4];
    const int*   snnz   = (const int*)d_in[5];
    float* out = (float*)d_out;

    // workspace layout: m[256*16], l[256*16], acc[256*16*128]  (~2.1 MB)
    float* ws_m   = (float*)d_ws;
    float* ws_l   = ws_m + BB * HH * NCHUNK;
    float* ws_acc = ws_l + BB * HH * NCHUNK;

    attn_partial<<<dim3(BB * HH * NCHUNK), dim3(256), 0, stream>>>(
        q, cache, indptr, pgind, sind, snnz, ws_m, ws_l, ws_acc);
    attn_combine<<<dim3(BB * HH), dim3(128), 0, stream>>>(
        ws_m, ws_l, ws_acc, out);
}